// Round 6
// baseline (76.963 us; speedup 1.0000x reference)
//
#include <hip/hip_runtime.h>
#include <stdint.h>

#define BB 8
#define SS 2048
#define DIN 768
#define DKV 64
#define NCHUNK (DIN / 32)   // 24 k-chunks of 32

typedef float f32x4 __attribute__((ext_vector_type(4)));
typedef float f32x16 __attribute__((ext_vector_type(16)));
typedef __bf16 bf16x8 __attribute__((ext_vector_type(8)));

// ---------------------------------------------------------------------------
// Kernel 0: pre-convert W (f32, [64,768]) to bf16 MFMA-B fragment layout.
// ---------------------------------------------------------------------------
__global__ void wconv_kernel(const float* __restrict__ Wq,
                             const float* __restrict__ Wk,
                             const float* __restrict__ Wv,
                             __bf16* __restrict__ wf)
{
    const int m = blockIdx.y;
    const float* W = (m == 0) ? Wq : (m == 1) ? Wk : Wv;
    const int kc = blockIdx.x;
    const int t = threadIdx.x;
    const int c = t >> 6, lane = t & 63;
    const int lo = lane & 15, hi = lane >> 4;
    const float* src = W + (size_t)(16 * c + lo) * DIN + 32 * kc + 8 * hi;
    bf16x8 v;
    #pragma unroll
    for (int j = 0; j < 8; j++) v[j] = (__bf16)src[j];
    *(bf16x8*)(wf + ((((size_t)m * NCHUNK + kc) * 4 + c) * 64 + lane) * 8) = v;
}

// ---------------------------------------------------------------------------
// Kernel 1: fused projections, split-K x2 within the block.
// Block = 512 thr (8 waves): wave = rg + 4*kh; row-group rg owns 16 rows,
// k-half kh owns 12 of 24 chunks.  Fully-unrolled 12-chunk loop, 4-deep A /
// 3-deep W register stages (all indices compile-time).  K-halves combined
// via LDS f32 tile, kh=0 waves do bias+cvt+store.
// (512,4): 128-VGPR cap -> ~112 used, no spill; 6144 waves total.
// ---------------------------------------------------------------------------
__global__ __launch_bounds__(512, 4) void proj_kernel(
    const float* __restrict__ Aq, const float* __restrict__ Ak, const float* __restrict__ Av,
    const __bf16* __restrict__ wf,
    const float* __restrict__ bq, const float* __restrict__ bk, const float* __restrict__ bv,
    __bf16* __restrict__ q_ws, __bf16* __restrict__ k_ws, __bf16* __restrict__ vT_ws)
{
    __shared__ float o_lds[4][16][66];   // 16.9 KB, 2-way bank alias = free

    const int which = blockIdx.y;
    const float* A; const float* bias;
    if (which == 0)      { A = Aq; bias = bq; }
    else if (which == 1) { A = Ak; bias = bk; }
    else                 { A = Av; bias = bv; }
    const __bf16* wfm = wf + (size_t)which * NCHUNK * 4 * 64 * 8;

    const int w8 = threadIdx.x >> 6;
    const int rg = w8 & 3;               // row-group 0..3
    const int kh = w8 >> 2;              // k-half 0..1 (12 chunks each)
    const int lane = threadIdx.x & 63;
    const int lo = lane & 15, hi = lane >> 4;
    const int row = blockIdx.x * 64 + rg * 16 + lo;
    const float* arow = A + (size_t)row * DIN + kh * (12 * 32);
    const __bf16* wbase = wfm + (size_t)kh * 12 * 4 * 64 * 8;

    #define LOADA(i, a0, a1)  do { \
        a0 = *(const f32x4*)(arow + 32 * (i) + 8 * hi); \
        a1 = *(const f32x4*)(arow + 32 * (i) + 8 * hi + 4); } while (0)
    #define LOADW(i, w)  do { \
        const __bf16* p_ = wbase + (((size_t)(i) * 256) + lane) * 8; \
        w[0] = *(const bf16x8*)(p_); \
        w[1] = *(const bf16x8*)(p_ + 64 * 8); \
        w[2] = *(const bf16x8*)(p_ + 128 * 8); \
        w[3] = *(const bf16x8*)(p_ + 192 * 8); } while (0)

    f32x4 a0s[4], a1s[4];
    bf16x8 ws[3][4];
    #pragma unroll
    for (int i = 0; i < 4; i++) LOADA(i, a0s[i], a1s[i]);
    #pragma unroll
    for (int i = 0; i < 3; i++) LOADW(i, ws[i]);

    f32x4 acc[4] = {};

    #pragma unroll
    for (int i = 0; i < 12; i++) {
        bf16x8 af;
        {
            const f32x4 a0 = a0s[i & 3], a1 = a1s[i & 3];
            #pragma unroll
            for (int j = 0; j < 4; j++) { af[j] = (__bf16)a0[j]; af[4 + j] = (__bf16)a1[j]; }
        }
        #pragma unroll
        for (int c = 0; c < 4; c++)
            acc[c] = __builtin_amdgcn_mfma_f32_16x16x32_bf16(af, ws[i % 3][c], acc[c], 0, 0, 0);
        if (i + 4 < 12) LOADA(i + 4, a0s[i & 3], a1s[i & 3]);
        if (i + 3 < 12) LOADW(i + 3, ws[i % 3]);
    }
    #undef LOADA
    #undef LOADW

    // ---- split-K combine: kh=1 publishes, kh=0 adds + epilogue ----
    if (kh == 1) {
        #pragma unroll
        for (int c = 0; c < 4; c++)
            #pragma unroll
            for (int r = 0; r < 4; r++)
                o_lds[rg][4 * hi + r][16 * c + lo] = acc[c][r];
    }
    __syncthreads();
    if (kh == 0) {
        const int orow_base = blockIdx.x * 64 + rg * 16 + 4 * hi;
        #pragma unroll
        for (int c = 0; c < 4; c++) {
            const int col = lo + 16 * c;
            const float bcol = bias[col];
            #pragma unroll
            for (int r = 0; r < 4; r++) {
                const int orow = orow_base + r;
                const float val = acc[c][r] + o_lds[rg][4 * hi + r][col] + bcol;
                const int b = orow >> 11;
                const int s = orow & 2047;
                if (which == 0)      q_ws[((size_t)b * SS + s) * DKV + col] = (__bf16)val;
                else if (which == 1) k_ws[((size_t)b * SS + s) * DKV + col] = (__bf16)val;
                else                 vT_ws[((size_t)b * DKV + col) * SS + s] = (__bf16)val;
            }
        }
    }
}

// ---------------------------------------------------------------------------
// Kernel 2: flash attention v3 (unchanged from round 5) — swapped QK^T
// (mfma(K,Q) -> D[key][q]) with 32x32x16 MFMA, in-register softmax, mask as
// MFMA C-init bias, pack+shfl P exchange, 8-wave KV-split + LDS combine.
// ---------------------------------------------------------------------------
#define NW 8
#define CEXP 0.18033688011f    // 0.125 * log2(e)

__device__ inline uint32_t pk2(float a, float b) {
    union { __bf16 h[2]; uint32_t u; } z;
    z.h[0] = (__bf16)a; z.h[1] = (__bf16)b;
    return z.u;
}

__global__ __launch_bounds__(512, 4) void attn_kernel(
    const __bf16* __restrict__ q_ws, const __bf16* __restrict__ k_ws,
    const __bf16* __restrict__ vT_ws, const int* __restrict__ mask,
    float* __restrict__ out)
{
    __shared__ float bias_lds[SS];          // 8 KB   (bias*8: 0 or -8e30)
    __shared__ float ml_lds[NW][2][32];     // 2 KB
    __shared__ float o_lds[NW][32][66];     // 67.6 KB (pad 66: 2-way free)

    const int b = blockIdx.x & 7;              // batch == XCD (round-robin)
    const int qbase = (blockIdx.x >> 3) * 32;
    const int w = threadIdx.x >> 6;
    const int lane = threadIdx.x & 63;
    const int lq = lane & 31;                  // q for B-col / key,v for A-row
    const int h = lane >> 5;

    for (int i = threadIdx.x; i < SS; i += 512)
        bias_lds[i] = mask[b * SS + i] ? -8e30f : 0.0f;
    __syncthreads();

    // Q B-frags (persist): qbf[t][j] = Q[qbase+lq][16t + 8h + j]
    bf16x8 qbf[4];
    {
        const __bf16* qp = q_ws + ((size_t)b * SS + qbase + lq) * DKV + 8 * h;
        #pragma unroll
        for (int t = 0; t < 4; t++) qbf[t] = *(const bf16x8*)(qp + 16 * t);
    }

    f32x16 oacc0 = {}, oacc1 = {};   // D[v][q], v-halves 0-31 / 32-63
    float m = -3e38f, l = 0.f;       // per-lane: one q, own key-subset l

    #pragma unroll 1
    for (int it = 0; it < 8; ++it) {
        const int kv = w * 256 + it * 32;

        // ---- C-init = mask bias: acc[r] <- bias8[kv + 8*(r>>2) + 4h + (r&3)]
        f32x16 acc;
        #pragma unroll
        for (int g = 0; g < 4; g++) {
            f32x4 bg = *(const f32x4*)&bias_lds[kv + 8 * g + 4 * h];
            acc[4*g+0] = bg[0]; acc[4*g+1] = bg[1];
            acc[4*g+2] = bg[2]; acc[4*g+3] = bg[3];
        }

        // ---- QK^T: D[key][q], 4 d-steps of 16
        const __bf16* kp = k_ws + ((size_t)b * SS + kv + lq) * DKV + 8 * h;
        #pragma unroll
        for (int t = 0; t < 4; t++) {
            bf16x8 kaf = *(const bf16x8*)(kp + 16 * t);
            acc = __builtin_amdgcn_mfma_f32_32x32x16_bf16(kaf, qbf[t], acc, 0, 0, 0);
        }

        // ---- in-register block max (own 16 + partner half)
        float q0 = fmaxf(fmaxf(acc[0], acc[1]),  fmaxf(acc[2], acc[3]));
        float q1 = fmaxf(fmaxf(acc[4], acc[5]),  fmaxf(acc[6], acc[7]));
        float q2 = fmaxf(fmaxf(acc[8], acc[9]),  fmaxf(acc[10], acc[11]));
        float q3 = fmaxf(fmaxf(acc[12], acc[13]), fmaxf(acc[14], acc[15]));
        float mx = fmaxf(fmaxf(q0, q1), fmaxf(q2, q3));
        mx = fmaxf(mx, __shfl_xor(mx, 32));

        const float mnew = fmaxf(m, mx);
        const float alpha = exp2f((m - mnew) * CEXP);
        m = mnew;
        l *= alpha;
        #pragma unroll
        for (int r = 0; r < 16; r++) { oacc0[r] *= alpha; oacc1[r] *= alpha; }

        float p[16];
        #pragma unroll
        for (int r = 0; r < 16; r++) {
            p[r] = exp2f((acc[r] - mnew) * CEXP);
            l += p[r];
        }

        // ---- pack + half-exchange + PV (2 k-steps of 16 keys)
        #pragma unroll
        for (int s = 0; s < 2; s++) {
            const uint32_t X0 = pk2(p[8*s+0], p[8*s+1]);
            const uint32_t X1 = pk2(p[8*s+2], p[8*s+3]);
            const uint32_t Y0 = pk2(p[8*s+4], p[8*s+5]);
            const uint32_t Y1 = pk2(p[8*s+6], p[8*s+7]);
            const uint32_t s0 = h ? X0 : Y0;       // send what partner needs
            const uint32_t s1 = h ? X1 : Y1;
            const uint32_t c0 = __shfl_xor(s0, 32);
            const uint32_t c1 = __shfl_xor(s1, 32);
            union { uint32_t wd[4]; bf16x8 v; } fr;
            fr.wd[0] = h ? c0 : X0;
            fr.wd[1] = h ? c1 : X1;
            fr.wd[2] = h ? Y0 : c0;
            fr.wd[3] = h ? Y1 : c1;

            const __bf16* vp = vT_ws + ((size_t)b * DKV + lq) * SS
                               + kv + 16 * s + 8 * h;
            bf16x8 va0 = *(const bf16x8*)(vp);
            bf16x8 va1 = *(const bf16x8*)(vp + (size_t)32 * SS);
            oacc0 = __builtin_amdgcn_mfma_f32_32x32x16_bf16(va0, fr.v, oacc0, 0, 0, 0);
            oacc1 = __builtin_amdgcn_mfma_f32_32x32x16_bf16(va1, fr.v, oacc1, 0, 0, 0);
        }
    }

    l += __shfl_xor(l, 32);   // partner holds the other key-half's sum

    __syncthreads();          // everyone done with bias_lds-phase reads

    // ---- publish per-wave partials
    if (h == 0) { ml_lds[w][0][lq] = m; ml_lds[w][1][lq] = l; }
    #pragma unroll
    for (int r = 0; r < 16; r++) {
        const int v = (r & 3) + 8 * (r >> 2) + 4 * h;
        o_lds[w][lq][v]      = oacc0[r];
        o_lds[w][lq][32 + v] = oacc1[r];
    }
    __syncthreads();

    // ---- cross-wave flash combine: 2048 cells / 512 threads = 4 each
    for (int idx = threadIdx.x; idx < 32 * 64; idx += 512) {
        const int row = idx >> 6, col = idx & 63;
        float M = -3e38f;
        #pragma unroll
        for (int ww = 0; ww < NW; ww++) M = fmaxf(M, ml_lds[ww][0][row]);
        float L = 0.f, osum = 0.f;
        #pragma unroll
        for (int ww = 0; ww < NW; ww++) {
            const float a = exp2f((ml_lds[ww][0][row] - M) * CEXP);
            L += ml_lds[ww][1][row] * a;
            osum += o_lds[ww][row][col] * a;
        }
        out[((size_t)b * SS + qbase + row) * DKV + col] = osum / L;
    }
}

extern "C" void kernel_launch(void* const* d_in, const int* in_sizes, int n_in,
                              void* d_out, int out_size, void* d_ws, size_t ws_size,
                              hipStream_t stream)
{
    (void)in_sizes; (void)n_in; (void)out_size; (void)ws_size;
    const float* query = (const float*)d_in[0];
    const float* key_  = (const float*)d_in[1];
    const float* value = (const float*)d_in[2];
    const int*   mask  = (const int*)d_in[3];
    const float* Wq    = (const float*)d_in[4];
    const float* bq    = (const float*)d_in[5];
    const float* Wk    = (const float*)d_in[6];
    const float* bk    = (const float*)d_in[7];
    const float* Wv    = (const float*)d_in[8];
    const float* bv    = (const float*)d_in[9];
    float* out = (float*)d_out;

    __bf16* q_ws  = (__bf16*)d_ws;                         // 2 MB
    __bf16* k_ws  = q_ws + (size_t)BB * SS * DKV;          // 2 MB
    __bf16* vT_ws = k_ws + (size_t)BB * SS * DKV;          // 2 MB (transposed)
    __bf16* wf    = vT_ws + (size_t)BB * SS * DKV;         // 3 x 98 KB frag-W

    wconv_kernel<<<dim3(NCHUNK, 3, 1), 256, 0, stream>>>(Wq, Wk, Wv, wf);
    proj_kernel<<<dim3(256, 3, 1), 512, 0, stream>>>(
        query, key_, value, wf, bq, bk, bv, q_ws, k_ws, vT_ws);
    attn_kernel<<<dim3(SS / 32 * BB, 1, 1), 512, 0, stream>>>(
        q_ws, k_ws, vT_ws, mask, out);
}

// Round 7
// 73.390 us; speedup vs baseline: 1.0487x; 1.0487x over previous
//
#include <hip/hip_runtime.h>
#include <stdint.h>

#define BB 8
#define SS 2048
#define DIN 768
#define DKV 64
#define NCHUNK (DIN / 32)   // 24 k-chunks of 32
#define NSTEP (DIN / 64)    // 12 K-steps of 64 floats (2 chunks each)

typedef float f32x4 __attribute__((ext_vector_type(4)));
typedef float f32x16 __attribute__((ext_vector_type(16)));
typedef __bf16 bf16x8 __attribute__((ext_vector_type(8)));

#define AS1(p) ((const __attribute__((address_space(1))) uint32_t*)(p))
#define AS3(p) ((__attribute__((address_space(3))) uint32_t*)(p))

// ---------------------------------------------------------------------------
// Kernel 0: pre-convert W (f32, [64,768]) to bf16 MFMA-B fragment layout.
// ---------------------------------------------------------------------------
__global__ void wconv_kernel(const float* __restrict__ Wq,
                             const float* __restrict__ Wk,
                             const float* __restrict__ Wv,
                             __bf16* __restrict__ wf)
{
    const int m = blockIdx.y;
    const float* W = (m == 0) ? Wq : (m == 1) ? Wk : Wv;
    const int kc = blockIdx.x;
    const int t = threadIdx.x;
    const int c = t >> 6, lane = t & 63;
    const int lo = lane & 15, hi = lane >> 4;
    const float* src = W + (size_t)(16 * c + lo) * DIN + 32 * kc + 8 * hi;
    bf16x8 v;
    #pragma unroll
    for (int j = 0; j < 8; j++) v[j] = (__bf16)src[j];
    *(bf16x8*)(wf + ((((size_t)m * NCHUNK + kc) * 4 + c) * 64 + lane) * 8) = v;
}

// ---------------------------------------------------------------------------
// Kernel 1: fused projections, m97-style global_load_lds staging.
// Block = 256 thr (4 waves) x 64 rows.  A staged f32 into double-buffered
// LDS [2][64][64] via width-16 global_load_lds (1 KB contiguous per
// wave-instr, coalesced).  16B-unit XOR swizzle (u ^ row&15) applied on the
// per-lane GLOBAL source + on the ds_read address (linear LDS dest).
// One barrier per K-step: stage(t+1) overlaps compute(t).
// ---------------------------------------------------------------------------
__global__ __launch_bounds__(256, 4) void proj_kernel(
    const float* __restrict__ Aq, const float* __restrict__ Ak, const float* __restrict__ Av,
    const __bf16* __restrict__ wf,
    const float* __restrict__ bq, const float* __restrict__ bk, const float* __restrict__ bv,
    __bf16* __restrict__ q_ws, __bf16* __restrict__ k_ws, __bf16* __restrict__ vT_ws)
{
    __shared__ __align__(16) float abuf[2][64][64];   // 32 KB

    const int which = blockIdx.y;
    const float* A; const float* bias;
    if (which == 0)      { A = Aq; bias = bq; }
    else if (which == 1) { A = Ak; bias = bk; }
    else                 { A = Av; bias = bv; }
    const __bf16* wfm = wf + (size_t)which * NCHUNK * 4 * 64 * 8;

    const int w = threadIdx.x >> 6;
    const int lane = threadIdx.x & 63;
    const int lo = lane & 15, hi = lane >> 4;
    const int brow = blockIdx.x * 64;

    // per-lane source-row/unit for staging (instr j covers 4 rows):
    //   row_local = 16w + 4j + (lane>>4); pos = lane&15; global unit = pos^row
    const int srl = 16 * w + (lane >> 4);          // + 4j
    const float* asrc = A + (size_t)(brow + srl) * DIN;

    #define STAGE(t, bsel) do { \
        _Pragma("unroll") \
        for (int j = 0; j < 4; j++) { \
            const int u_ = (lane & 15) ^ ((srl + 4 * j) & 15); \
            const float* s_ = asrc + (size_t)(4 * j) * DIN + (t) * 64 + u_ * 4; \
            __builtin_amdgcn_global_load_lds(AS1(s_), AS3(&abuf[bsel][16 * w + 4 * j][0]), 16, 0, 0); \
        } } while (0)

    f32x4 acc[4] = {};

    STAGE(0, 0);
    __syncthreads();

    #pragma unroll 1
    for (int t = 0; t < NSTEP; ++t) {
        if (t + 1 < NSTEP) {
            if ((t & 1) == 0) STAGE(t + 1, 1); else STAGE(t + 1, 0);
        }

        const float* lp = &abuf[t & 1][16 * w + lo][0];
        #pragma unroll
        for (int cc = 0; cc < 2; cc++) {
            const int u0 = 8 * cc + 2 * hi;
            f32x4 a0 = *(const f32x4*)(lp + 4 * (u0 ^ lo));
            f32x4 a1 = *(const f32x4*)(lp + 4 * ((u0 + 1) ^ lo));
            bf16x8 af;
            #pragma unroll
            for (int j = 0; j < 4; j++) { af[j] = (__bf16)a0[j]; af[4 + j] = (__bf16)a1[j]; }

            const __bf16* p_ = wfm + (((size_t)(2 * t + cc) * 256) + lane) * 8;
            #pragma unroll
            for (int c = 0; c < 4; c++) {
                bf16x8 wv = *(const bf16x8*)(p_ + (size_t)c * 512);
                acc[c] = __builtin_amdgcn_mfma_f32_16x16x32_bf16(af, wv, acc[c], 0, 0, 0);
            }
        }
        __syncthreads();   // drains stage(t+1) vmcnt + all reads of buf[t&1]
    }
    #undef STAGE

    // ---- epilogue: D col=lo+16c, row=4hi+r ----
    const int orow_base = brow + 16 * w + 4 * hi;
    #pragma unroll
    for (int c = 0; c < 4; c++) {
        const int col = lo + 16 * c;
        const float bcol = bias[col];
        #pragma unroll
        for (int r = 0; r < 4; r++) {
            const int orow = orow_base + r;
            const float val = acc[c][r] + bcol;
            const int b = orow >> 11;
            const int s = orow & 2047;
            if (which == 0)      q_ws[((size_t)b * SS + s) * DKV + col] = (__bf16)val;
            else if (which == 1) k_ws[((size_t)b * SS + s) * DKV + col] = (__bf16)val;
            else                 vT_ws[((size_t)b * DKV + col) * SS + s] = (__bf16)val;
        }
    }
}

// ---------------------------------------------------------------------------
// Kernel 2: flash attention v3 (unchanged from round 5) — swapped QK^T
// (mfma(K,Q) -> D[key][q]) with 32x32x16 MFMA, in-register softmax, mask as
// MFMA C-init bias, pack+shfl P exchange, 8-wave KV-split + LDS combine.
// ---------------------------------------------------------------------------
#define NW 8
#define CEXP 0.18033688011f    // 0.125 * log2(e)

__device__ inline uint32_t pk2(float a, float b) {
    union { __bf16 h[2]; uint32_t u; } z;
    z.h[0] = (__bf16)a; z.h[1] = (__bf16)b;
    return z.u;
}

__global__ __launch_bounds__(512, 4) void attn_kernel(
    const __bf16* __restrict__ q_ws, const __bf16* __restrict__ k_ws,
    const __bf16* __restrict__ vT_ws, const int* __restrict__ mask,
    float* __restrict__ out)
{
    __shared__ float bias_lds[SS];          // 8 KB   (bias*8: 0 or -8e30)
    __shared__ float ml_lds[NW][2][32];     // 2 KB
    __shared__ float o_lds[NW][32][66];     // 67.6 KB (pad 66: 2-way free)

    const int b = blockIdx.x & 7;              // batch == XCD (round-robin)
    const int qbase = (blockIdx.x >> 3) * 32;
    const int w = threadIdx.x >> 6;
    const int lane = threadIdx.x & 63;
    const int lq = lane & 31;                  // q for B-col / key,v for A-row
    const int h = lane >> 5;

    for (int i = threadIdx.x; i < SS; i += 512)
        bias_lds[i] = mask[b * SS + i] ? -8e30f : 0.0f;
    __syncthreads();

    // Q B-frags (persist): qbf[t][j] = Q[qbase+lq][16t + 8h + j]
    bf16x8 qbf[4];
    {
        const __bf16* qp = q_ws + ((size_t)b * SS + qbase + lq) * DKV + 8 * h;
        #pragma unroll
        for (int t = 0; t < 4; t++) qbf[t] = *(const bf16x8*)(qp + 16 * t);
    }

    f32x16 oacc0 = {}, oacc1 = {};   // D[v][q], v-halves 0-31 / 32-63
    float m = -3e38f, l = 0.f;       // per-lane: one q, own key-subset l

    #pragma unroll 1
    for (int it = 0; it < 8; ++it) {
        const int kv = w * 256 + it * 32;

        // ---- C-init = mask bias: acc[r] <- bias8[kv + 8*(r>>2) + 4h + (r&3)]
        f32x16 acc;
        #pragma unroll
        for (int g = 0; g < 4; g++) {
            f32x4 bg = *(const f32x4*)&bias_lds[kv + 8 * g + 4 * h];
            acc[4*g+0] = bg[0]; acc[4*g+1] = bg[1];
            acc[4*g+2] = bg[2]; acc[4*g+3] = bg[3];
        }

        // ---- QK^T: D[key][q], 4 d-steps of 16
        const __bf16* kp = k_ws + ((size_t)b * SS + kv + lq) * DKV + 8 * h;
        #pragma unroll
        for (int t = 0; t < 4; t++) {
            bf16x8 kaf = *(const bf16x8*)(kp + 16 * t);
            acc = __builtin_amdgcn_mfma_f32_32x32x16_bf16(kaf, qbf[t], acc, 0, 0, 0);
        }

        // ---- in-register block max (own 16 + partner half)
        float q0 = fmaxf(fmaxf(acc[0], acc[1]),  fmaxf(acc[2], acc[3]));
        float q1 = fmaxf(fmaxf(acc[4], acc[5]),  fmaxf(acc[6], acc[7]));
        float q2 = fmaxf(fmaxf(acc[8], acc[9]),  fmaxf(acc[10], acc[11]));
        float q3 = fmaxf(fmaxf(acc[12], acc[13]), fmaxf(acc[14], acc[15]));
        float mx = fmaxf(fmaxf(q0, q1), fmaxf(q2, q3));
        mx = fmaxf(mx, __shfl_xor(mx, 32));

        const float mnew = fmaxf(m, mx);
        const float alpha = exp2f((m - mnew) * CEXP);
        m = mnew;
        l *= alpha;
        #pragma unroll
        for (int r = 0; r < 16; r++) { oacc0[r] *= alpha; oacc1[r] *= alpha; }

        float p[16];
        #pragma unroll
        for (int r = 0; r < 16; r++) {
            p[r] = exp2f((acc[r] - mnew) * CEXP);
            l += p[r];
        }

        // ---- pack + half-exchange + PV (2 k-steps of 16 keys)
        #pragma unroll
        for (int s = 0; s < 2; s++) {
            const uint32_t X0 = pk2(p[8*s+0], p[8*s+1]);
            const uint32_t X1 = pk2(p[8*s+2], p[8*s+3]);
            const uint32_t Y0 = pk2(p[8*s+4], p[8*s+5]);
            const uint32_t Y1 = pk2(p[8*s+6], p[8*s+7]);
            const uint32_t s0 = h ? X0 : Y0;       // send what partner needs
            const uint32_t s1 = h ? X1 : Y1;
            const uint32_t c0 = __shfl_xor(s0, 32);
            const uint32_t c1 = __shfl_xor(s1, 32);
            union { uint32_t wd[4]; bf16x8 v; } fr;
            fr.wd[0] = h ? c0 : X0;
            fr.wd[1] = h ? c1 : X1;
            fr.wd[2] = h ? Y0 : c0;
            fr.wd[3] = h ? Y1 : c1;

            const __bf16* vp = vT_ws + ((size_t)b * DKV + lq) * SS
                               + kv + 16 * s + 8 * h;
            bf16x8 va0 = *(const bf16x8*)(vp);
            bf16x8 va1 = *(const bf16x8*)(vp + (size_t)32 * SS);
            oacc0 = __builtin_amdgcn_mfma_f32_32x32x16_bf16(va0, fr.v, oacc0, 0, 0, 0);
            oacc1 = __builtin_amdgcn_mfma_f32_32x32x16_bf16(va1, fr.v, oacc1, 0, 0, 0);
        }
    }

    l += __shfl_xor(l, 32);   // partner holds the other key-half's sum

    __syncthreads();          // everyone done with bias_lds-phase reads

    // ---- publish per-wave partials
    if (h == 0) { ml_lds[w][0][lq] = m; ml_lds[w][1][lq] = l; }
    #pragma unroll
    for (int r = 0; r < 16; r++) {
        const int v = (r & 3) + 8 * (r >> 2) + 4 * h;
        o_lds[w][lq][v]      = oacc0[r];
        o_lds[w][lq][32 + v] = oacc1[r];
    }
    __syncthreads();

    // ---- cross-wave flash combine: 2048 cells / 512 threads = 4 each
    for (int idx = threadIdx.x; idx < 32 * 64; idx += 512) {
        const int row = idx >> 6, col = idx & 63;
        float M = -3e38f;
        #pragma unroll
        for (int ww = 0; ww < NW; ww++) M = fmaxf(M, ml_lds[ww][0][row]);
        float L = 0.f, osum = 0.f;
        #pragma unroll
        for (int ww = 0; ww < NW; ww++) {
            const float a = exp2f((ml_lds[ww][0][row] - M) * CEXP);
            L += ml_lds[ww][1][row] * a;
            osum += o_lds[ww][row][col] * a;
        }
        out[((size_t)b * SS + qbase + row) * DKV + col] = osum / L;
    }
}

extern "C" void kernel_launch(void* const* d_in, const int* in_sizes, int n_in,
                              void* d_out, int out_size, void* d_ws, size_t ws_size,
                              hipStream_t stream)
{
    (void)in_sizes; (void)n_in; (void)out_size; (void)ws_size;
    const float* query = (const float*)d_in[0];
    const float* key_  = (const float*)d_in[1];
    const float* value = (const float*)d_in[2];
    const int*   mask  = (const int*)d_in[3];
    const float* Wq    = (const float*)d_in[4];
    const float* bq    = (const float*)d_in[5];
    const float* Wk    = (const float*)d_in[6];
    const float* bk    = (const float*)d_in[7];
    const float* Wv    = (const float*)d_in[8];
    const float* bv    = (const float*)d_in[9];
    float* out = (float*)d_out;

    __bf16* q_ws  = (__bf16*)d_ws;                         // 2 MB
    __bf16* k_ws  = q_ws + (size_t)BB * SS * DKV;          // 2 MB
    __bf16* vT_ws = k_ws + (size_t)BB * SS * DKV;          // 2 MB (transposed)
    __bf16* wf    = vT_ws + (size_t)BB * SS * DKV;         // 3 x 98 KB frag-W

    wconv_kernel<<<dim3(NCHUNK, 3, 1), 256, 0, stream>>>(Wq, Wk, Wv, wf);
    proj_kernel<<<dim3(256, 3, 1), 256, 0, stream>>>(
        query, key_, value, wf, bq, bk, bv, q_ws, k_ws, vT_ws);
    attn_kernel<<<dim3(SS / 32 * BB, 1, 1), 512, 0, stream>>>(
        q_ws, k_ws, vT_ws, mask, out);
}